// Round 13
// baseline (292.946 us; speedup 1.0000x reference)
//
#include <hip/hip_runtime.h>

#define NM 2048
#define EM 32768
#define NP 8192
#define EP 262144

typedef __attribute__((ext_vector_type(8))) short short8;
typedef __attribute__((ext_vector_type(4))) short short4v;
typedef __attribute__((ext_vector_type(4))) float f32x4;
typedef __attribute__((ext_vector_type(16))) float f32x16;

#define LOG2E 1.44269504088896340736f

__device__ __forceinline__ float e2(float x) { return __builtin_amdgcn_exp2f(x); }
__device__ __forceinline__ unsigned int pk_bf16_tr(float a, float b) {
    return __builtin_amdgcn_perm(__float_as_uint(a), __float_as_uint(b), 0x03020706u);
}
__device__ __forceinline__ unsigned short cvt_bf16(float f) {
    unsigned int u = __float_as_uint(f);
    u = (u + 0x7fff + ((u >> 16) & 1)) >> 16;   // RNE
    return (unsigned short)u;
}

// ------- phase 1: weight prep (blocks 0..159) + histogram (blocks 160..) fused -------
__global__ __launch_bounds__(256) void prep_hist_kernel(
    const float* __restrict__ w0, const float* __restrict__ w1, const float* __restrict__ w2,
    const float* __restrict__ w3, const float* __restrict__ w4, const float* __restrict__ w5,
    const float* __restrict__ w6, const float* __restrict__ w7, const float* __restrict__ w8,
    const float* __restrict__ w9, unsigned short* __restrict__ wt,
    const int* __restrict__ ei_m, const int* __restrict__ ei_p,
    int* __restrict__ cnt_m, int* __restrict__ cnt_p)
{
    int b = blockIdx.x;
    if (b < 160) {
        int t = b >> 4;                       // matrix 0..9 (16 blocks each)
        int e = (b & 15) * 256 + threadIdx.x;
        const float* src;
        switch (t) {
            case 0: src = w0; break; case 1: src = w1; break; case 2: src = w2; break;
            case 3: src = w3; break; case 4: src = w4; break; case 5: src = w5; break;
            case 6: src = w6; break; case 7: src = w7; break; case 8: src = w8; break;
            default: src = w9; break;
        }
        int n = e >> 6, k = e & 63;
        wt[t * 4096 + e] = cvt_bf16(src[k * 64 + n]);   // wt[t][n*64+k] = W[k][n]
        return;
    }
    int idx = (b - 160) * 256 + threadIdx.x;
    if (idx < EM) atomicAdd(&cnt_m[ei_m[EM + idx]], 1);
    int j = idx - EM;
    if (j >= 0 && j < EP) atomicAdd(&cnt_p[ei_p[EP + j]], 1);
}

// ---------------- phase 2: exclusive prefix sum (block 0 = mol, block 1 = prot) ----------------
__global__ __launch_bounds__(256) void scan_kernel(
    const int* __restrict__ cnt_m, const int* __restrict__ cnt_p,
    int* __restrict__ start_m, int* __restrict__ start_p,
    int* __restrict__ cur_m, int* __restrict__ cur_p)
{
    const int* cnt; int* start; int* cur; int n;
    if (blockIdx.x == 0) { cnt = cnt_m; start = start_m; cur = cur_m; n = NM; }
    else                 { cnt = cnt_p; start = start_p; cur = cur_p; n = NP; }
    int per = n >> 8;
    int tid = threadIdx.x;
    int base = tid * per;
    int s = 0;
    for (int i = 0; i < per; i++) s += cnt[base + i];
    __shared__ int wsum[4];
    int lane = tid & 63, w = tid >> 6;
    int v = s;
    #pragma unroll
    for (int off = 1; off < 64; off <<= 1) {
        int u = __shfl_up(v, off, 64);
        if (lane >= off) v += u;
    }
    if (lane == 63) wsum[w] = v;
    __syncthreads();
    int wo = 0;
    for (int i = 0; i < w; i++) wo += wsum[i];
    int run = wo + v - s;
    for (int i = 0; i < per; i++) {
        start[base + i] = run; cur[base + i] = run;
        run += cnt[base + i];
    }
    if (tid == 255) start[n] = run;
}

// ------- phase 3: scatter packed (edge<<sh)|src into dst-sorted order -------
__global__ __launch_bounds__(256) void scatter_kernel(
    const int* __restrict__ ei_m, const int* __restrict__ ei_p,
    int* __restrict__ cur_m, int* __restrict__ cur_p,
    int* __restrict__ pidx_m, int* __restrict__ pidx_p)
{
    int idx = blockIdx.x * 256 + threadIdx.x;
    if (idx < EM) {
        int d = ei_m[EM + idx];
        int pos = atomicAdd(&cur_m[d], 1);
        pidx_m[pos] = (idx << 11) | ei_m[idx];          // NM=2048 -> 11 src bits
    }
    int j = idx - EM;
    if (j >= 0 && j < EP) {
        int d = ei_p[EP + j];
        int pos = atomicAdd(&cur_p[d], 1);
        pidx_p[pos] = (j << 13) | ei_p[j];              // NP=8192 -> 13 src bits
    }
}

// ------- phase 4: segmented reduce; h0 = x + mean(relu(x[src]+ea)) -> bf16 -------
__global__ __launch_bounds__(256) void node_aggr_kernel(
    const float* __restrict__ x_m, const float* __restrict__ ea_m,
    const int* __restrict__ start_m, const int* __restrict__ pidx_m,
    const float* __restrict__ x_p, const float* __restrict__ ea_p,
    const int* __restrict__ start_p, const int* __restrict__ pidx_p,
    unsigned short* __restrict__ h0b_m, unsigned short* __restrict__ h0b_p)
{
    int wave = threadIdx.x >> 6, lane = threadIdx.x & 63;
    int nid = blockIdx.x * 4 + wave;
    const float *x, *ea; const int *start, *pidx; unsigned short* h0b; int n, sh, msk;
    if (nid < NM) { x = x_m; ea = ea_m; start = start_m; pidx = pidx_m; h0b = h0b_m; n = nid; sh = 11; msk = 2047; }
    else          { x = x_p; ea = ea_p; start = start_p; pidx = pidx_p; h0b = h0b_p; n = nid - NM; sh = 13; msk = 8191; }
    int b  = __builtin_amdgcn_readfirstlane(start[n]);
    int e  = __builtin_amdgcn_readfirstlane(start[n + 1]);
    int deg = e - b;
    const int* pp = pidx + b;
    float acc = 0.f;
    int j = 0;
    for (; j + 8 <= deg; j += 8) {
        int v0 = __builtin_amdgcn_readfirstlane(pp[j]);
        int v1 = __builtin_amdgcn_readfirstlane(pp[j + 1]);
        int v2 = __builtin_amdgcn_readfirstlane(pp[j + 2]);
        int v3 = __builtin_amdgcn_readfirstlane(pp[j + 3]);
        int v4 = __builtin_amdgcn_readfirstlane(pp[j + 4]);
        int v5 = __builtin_amdgcn_readfirstlane(pp[j + 5]);
        int v6 = __builtin_amdgcn_readfirstlane(pp[j + 6]);
        int v7 = __builtin_amdgcn_readfirstlane(pp[j + 7]);
        float a0 = ea[(size_t)(((unsigned)v0) >> sh) * 64 + lane];
        float a1 = ea[(size_t)(((unsigned)v1) >> sh) * 64 + lane];
        float a2 = ea[(size_t)(((unsigned)v2) >> sh) * 64 + lane];
        float a3 = ea[(size_t)(((unsigned)v3) >> sh) * 64 + lane];
        float a4 = ea[(size_t)(((unsigned)v4) >> sh) * 64 + lane];
        float a5 = ea[(size_t)(((unsigned)v5) >> sh) * 64 + lane];
        float a6 = ea[(size_t)(((unsigned)v6) >> sh) * 64 + lane];
        float a7 = ea[(size_t)(((unsigned)v7) >> sh) * 64 + lane];
        float y0 = x[(size_t)(v0 & msk) * 64 + lane];
        float y1 = x[(size_t)(v1 & msk) * 64 + lane];
        float y2 = x[(size_t)(v2 & msk) * 64 + lane];
        float y3 = x[(size_t)(v3 & msk) * 64 + lane];
        float y4 = x[(size_t)(v4 & msk) * 64 + lane];
        float y5 = x[(size_t)(v5 & msk) * 64 + lane];
        float y6 = x[(size_t)(v6 & msk) * 64 + lane];
        float y7 = x[(size_t)(v7 & msk) * 64 + lane];
        acc += fmaxf(y0 + a0, 0.f); acc += fmaxf(y1 + a1, 0.f);
        acc += fmaxf(y2 + a2, 0.f); acc += fmaxf(y3 + a3, 0.f);
        acc += fmaxf(y4 + a4, 0.f); acc += fmaxf(y5 + a5, 0.f);
        acc += fmaxf(y6 + a6, 0.f); acc += fmaxf(y7 + a7, 0.f);
    }
    for (; j < deg; ++j) {
        int v0 = __builtin_amdgcn_readfirstlane(pp[j]);
        acc += fmaxf(x[(size_t)(v0 & msk) * 64 + lane] + ea[(size_t)(((unsigned)v0) >> sh) * 64 + lane], 0.f);
    }
    float aggr = acc / fmaxf((float)deg, 1.f);
    h0b[(size_t)n * 64 + lane] = cvt_bf16(x[(size_t)n * 64 + lane] + aggr);
}

// ------- MFMA MLP+QKV: one wave per 16-row tile (64-thread blocks), zero barriers -------
__global__ __launch_bounds__(64) void mlp_qkv_kernel(
    const unsigned short* __restrict__ h0b_m, const unsigned short* __restrict__ h0b_p,
    const unsigned short* __restrict__ wt,
    const float* __restrict__ b1m_, const float* __restrict__ b2m_,
    const float* __restrict__ bqm_, const float* __restrict__ bkm_, const float* __restrict__ bvm_,
    const float* __restrict__ b1p_, const float* __restrict__ b2p_,
    const float* __restrict__ bqp_, const float* __restrict__ bkp_, const float* __restrict__ bvp_,
    float* __restrict__ hm, float* __restrict__ hp,
    unsigned short* __restrict__ Qm, unsigned short* __restrict__ Km, unsigned short* __restrict__ Vtm,
    unsigned short* __restrict__ Qp, unsigned short* __restrict__ Kp, unsigned short* __restrict__ Vtp,
    int* __restrict__ norms)
{
    __shared__ unsigned short tile[2][16][72];
    int lane = threadIdx.x & 63;
    int col = lane & 15, quad = lane >> 4;
    int blk = blockIdx.x;
    const unsigned short* h0b; const float *b1, *b2, *bq, *bk, *bv;
    float* hout; unsigned short *Q, *K, *Vt; int N, row0, wofs, nb;
    if (blk < NM / 16) {
        h0b = h0b_m; b1 = b1m_; b2 = b2m_; bq = bqm_; bk = bkm_; bv = bvm_;
        hout = hm; Q = Qm; K = Km; Vt = Vtm; N = NM;
        row0 = blk * 16; wofs = 0; nb = 0;
    } else {
        h0b = h0b_p; b1 = b1p_; b2 = b2p_; bq = bqp_; bk = bkp_; bv = bvp_;
        hout = hp; Q = Qp; K = Kp; Vt = Vtp; N = NP;
        row0 = (blk - NM / 16) * 16; wofs = 5 * 4096; nb = 2;
    }
    const f32x4 zero4 = {0.f, 0.f, 0.f, 0.f};
    const unsigned short* wb = wt + wofs + (size_t)col * 64 + quad * 8;

    const unsigned short* ar = h0b + (size_t)(row0 + col) * 64 + quad * 8;
    short8 aL = *(const short8*)ar;
    short8 aH = *(const short8*)(ar + 32);

    // ---- GEMM1: hidden = relu(h0@W1+b1) -> LDS buf0 ----
    #pragma unroll
    for (int nt = 0; nt < 4; ++nt) {
        short8 bL = *(const short8*)(wb + nt * 1024);
        short8 bH = *(const short8*)(wb + nt * 1024 + 32);
        f32x4 d = __builtin_amdgcn_mfma_f32_16x16x32_bf16(aL, bL, zero4, 0, 0, 0);
        d = __builtin_amdgcn_mfma_f32_16x16x32_bf16(aH, bH, d, 0, 0, 0);
        float bias = b1[nt * 16 + col];
        #pragma unroll
        for (int r = 0; r < 4; ++r)
            tile[0][quad * 4 + r][nt * 16 + col] = cvt_bf16(fmaxf(d[r] + bias, 0.f));
    }
    short8 a1L = *(const short8*)&tile[0][col][quad * 8];
    short8 a1H = *(const short8*)&tile[0][col][32 + quad * 8];

    // ---- GEMM2: h = relu(hidden@W2+b2) -> global fp32 + LDS buf1 ----
    #pragma unroll
    for (int nt = 0; nt < 4; ++nt) {
        short8 bL = *(const short8*)(wb + 4096 + nt * 1024);
        short8 bH = *(const short8*)(wb + 4096 + nt * 1024 + 32);
        f32x4 d = __builtin_amdgcn_mfma_f32_16x16x32_bf16(a1L, bL, zero4, 0, 0, 0);
        d = __builtin_amdgcn_mfma_f32_16x16x32_bf16(a1H, bH, d, 0, 0, 0);
        float bias = b2[nt * 16 + col];
        #pragma unroll
        for (int r = 0; r < 4; ++r) {
            float v = fmaxf(d[r] + bias, 0.f);
            hout[(size_t)(row0 + quad * 4 + r) * 64 + nt * 16 + col] = v;
            tile[1][quad * 4 + r][nt * 16 + col] = cvt_bf16(v);
        }
    }
    short8 a2L = *(const short8*)&tile[1][col][quad * 8];
    short8 a2H = *(const short8*)&tile[1][col][32 + quad * 8];

    // ---- GEMM3: Q (scaled into exp2 domain) + row-norm ----
    float q2[4] = {0.f, 0.f, 0.f, 0.f};
    #pragma unroll
    for (int nt = 0; nt < 4; ++nt) {
        short8 bL = *(const short8*)(wb + 2 * 4096 + nt * 1024);
        short8 bH = *(const short8*)(wb + 2 * 4096 + nt * 1024 + 32);
        f32x4 d = __builtin_amdgcn_mfma_f32_16x16x32_bf16(a2L, bL, zero4, 0, 0, 0);
        d = __builtin_amdgcn_mfma_f32_16x16x32_bf16(a2H, bH, d, 0, 0, 0);
        float bias = bq[nt * 16 + col];
        #pragma unroll
        for (int r = 0; r < 4; ++r) {
            float qv = (d[r] + bias) * (0.25f * LOG2E);
            Q[(size_t)(row0 + quad * 4 + r) * 64 + nt * 16 + col] = cvt_bf16(qv);
            q2[r] += qv * qv;
        }
    }
    float qmx = 0.f;
    #pragma unroll
    for (int r = 0; r < 4; ++r) {
        float s = q2[r];
        s += __shfl_xor(s, 1, 64); s += __shfl_xor(s, 2, 64);
        s += __shfl_xor(s, 4, 64); s += __shfl_xor(s, 8, 64);
        qmx = fmaxf(qmx, s);   // full-row sumsq >= any head sumsq -> valid C-S bound
    }

    // ---- GEMM4: K + row-norm ----
    float k2[4] = {0.f, 0.f, 0.f, 0.f};
    #pragma unroll
    for (int nt = 0; nt < 4; ++nt) {
        short8 bL = *(const short8*)(wb + 3 * 4096 + nt * 1024);
        short8 bH = *(const short8*)(wb + 3 * 4096 + nt * 1024 + 32);
        f32x4 d = __builtin_amdgcn_mfma_f32_16x16x32_bf16(a2L, bL, zero4, 0, 0, 0);
        d = __builtin_amdgcn_mfma_f32_16x16x32_bf16(a2H, bH, d, 0, 0, 0);
        float bias = bk[nt * 16 + col];
        #pragma unroll
        for (int r = 0; r < 4; ++r) {
            float kv = d[r] + bias;
            K[(size_t)(row0 + quad * 4 + r) * 64 + nt * 16 + col] = cvt_bf16(kv);
            k2[r] += kv * kv;
        }
    }
    float kmx = 0.f;
    #pragma unroll
    for (int r = 0; r < 4; ++r) {
        float s = k2[r];
        s += __shfl_xor(s, 1, 64); s += __shfl_xor(s, 2, 64);
        s += __shfl_xor(s, 4, 64); s += __shfl_xor(s, 8, 64);
        kmx = fmaxf(kmx, s);
    }

    // ---- GEMM5: V (transposed store) ----
    #pragma unroll
    for (int nt = 0; nt < 4; ++nt) {
        short8 bL = *(const short8*)(wb + 4 * 4096 + nt * 1024);
        short8 bH = *(const short8*)(wb + 4 * 4096 + nt * 1024 + 32);
        f32x4 d = __builtin_amdgcn_mfma_f32_16x16x32_bf16(a2L, bL, zero4, 0, 0, 0);
        d = __builtin_amdgcn_mfma_f32_16x16x32_bf16(a2H, bH, d, 0, 0, 0);
        float bias = bv[nt * 16 + col];
        short4v vv;
        vv.x = (short)cvt_bf16(d[0] + bias);
        vv.y = (short)cvt_bf16(d[1] + bias);
        vv.z = (short)cvt_bf16(d[2] + bias);
        vv.w = (short)cvt_bf16(d[3] + bias);
        *(short4v*)(Vt + (size_t)(nt * 16 + col) * N + row0 + quad * 4) = vv;
    }

    qmx = fmaxf(qmx, __shfl_xor(qmx, 16, 64)); qmx = fmaxf(qmx, __shfl_xor(qmx, 32, 64));
    kmx = fmaxf(kmx, __shfl_xor(kmx, 16, 64)); kmx = fmaxf(kmx, __shfl_xor(kmx, 32, 64));
    if (lane == 0) {
        atomicMax(&norms[nb],     __float_as_int(sqrtf(qmx)));
        atomicMax(&norms[nb + 1], __float_as_int(sqrtf(kmx)));
    }
}

// ------- MFMA flash-attention: 32x32x16 QK, fixed C-S bound m, deferred-PV pipeline -------
// 512-key chunks: mol NC=16, prot NC=4 -> 8192 wave-tasks, 2048 blocks (~7 blocks/CU).
__global__ __launch_bounds__(256) void attn_kernel(
    const unsigned short* __restrict__ Qm, const unsigned short* __restrict__ Km,
    const unsigned short* __restrict__ Vtm,
    const unsigned short* __restrict__ Qp, const unsigned short* __restrict__ Kp,
    const unsigned short* __restrict__ Vtp,
    const int* __restrict__ norms, float* __restrict__ partial)
{
    __shared__ unsigned int plds[4][2][2][16][20];   // [wave][qtile][buf][qrow][16+pad]
    int t = threadIdx.x;
    int wave = t >> 6;
    int lane = t & 63;
    int qrow = lane & 15;
    int quad = lane >> 4;
    int q5   = lane & 31;
    int half = lane >> 5;
    int qtl  = q5 >> 4;
    int dwb  = half * 2;
    int W = blockIdx.x * 4 + wave;

    const unsigned short *Q, *K, *Vt; int Nk; float m;
    int chunk, h, qt2, Tbase, T1off;
    if (W < 4096) {
        Q = Qm; K = Kp; Vt = Vtp; Nk = NP;
        m = __int_as_float(norms[0]) * __int_as_float(norms[3]);
        chunk = W & 15; h = (W >> 4) & 3; qt2 = W >> 6;
        Tbase = W + qt2 * 64; T1off = 64;
    } else {
        int W2 = W - 4096;
        Q = Qp; K = Km; Vt = Vtm; Nk = NM;
        m = __int_as_float(norms[2]) * __int_as_float(norms[1]);
        chunk = W2 & 3; h = (W2 >> 2) & 3; qt2 = W2 >> 4;
        Tbase = 8192 + W2 + qt2 * 16; T1off = 16;
    }

    short8 qf = *(const short8*)(Q + ((size_t)(qt2 * 32 + q5)) * 64 + h * 16 + half * 8);

    const f32x16 zero16 = {0.f,0.f,0.f,0.f,0.f,0.f,0.f,0.f,0.f,0.f,0.f,0.f,0.f,0.f,0.f,0.f};
    const f32x4 zero4 = {0.f, 0.f, 0.f, 0.f};
    int kbase = chunk * 512;
    const unsigned short* krow = K + (size_t)(kbase + q5) * 64 + h * 16 + half * 8;
    const unsigned short* vrow = Vt + ((size_t)(h * 16 + qrow)) * Nk + kbase + quad * 8;

    float l = 0.0f;
    f32x4 accA = zero4, accB = zero4;

    short8 kf_0, kf_1, vf_0, vf_1;
    kf_0 = *(const short8*)(krow);
    kf_1 = *(const short8*)(krow + 32 * 64);
    vf_0 = *(const short8*)(vrow);
    vf_1 = *(const short8*)(vrow + 32);

    short8 vf_prev;

#define QK_PHASE(IT, SLOT, BUF)                                                             \
    {                                                                                       \
        short8 kf = kf_##SLOT; short8 vf = vf_##SLOT;                                       \
        if ((IT) < 14) {                                                                    \
            int off = ((IT) + 2) * 32;                                                      \
            kf_##SLOT = *(const short8*)(krow + (size_t)off * 64);                          \
            vf_##SLOT = *(const short8*)(vrow + off);                                       \
        }                                                                                   \
        f32x16 s = __builtin_amdgcn_mfma_f32_32x32x16_bf16(kf, qf, zero16, 0, 0, 0);        \
        float p0  = e2(s[0] - m),  p1  = e2(s[1] - m),  p2  = e2(s[2] - m),  p3  = e2(s[3] - m);  \
        float p4  = e2(s[4] - m),  p5  = e2(s[5] - m),  p6  = e2(s[6] - m),  p7  = e2(s[7] - m);  \
        float p8  = e2(s[8] - m),  p9  = e2(s[9] - m),  p10 = e2(s[10] - m), p11 = e2(s[11] - m); \
        float p12 = e2(s[12] - m), p13 = e2(s[13] - m), p14 = e2(s[14] - m), p15 = e2(s[15] - m); \
        l += (((p0 + p1) + (p2 + p3)) + ((p4 + p5) + (p6 + p7)))                            \
           + (((p8 + p9) + (p10 + p11)) + ((p12 + p13) + (p14 + p15)));                     \
        uint2 w0; w0.x = pk_bf16_tr(p0, p1);   w0.y = pk_bf16_tr(p2, p3);                   \
        uint2 w1; w1.x = pk_bf16_tr(p4, p5);   w1.y = pk_bf16_tr(p6, p7);                   \
        uint2 w2; w2.x = pk_bf16_tr(p8, p9);   w2.y = pk_bf16_tr(p10, p11);                 \
        uint2 w3; w3.x = pk_bf16_tr(p12, p13); w3.y = pk_bf16_tr(p14, p15);                 \
        *(uint2*)&plds[wave][qtl][BUF][qrow][dwb]      = w0;                                \
        *(uint2*)&plds[wave][qtl][BUF][qrow][dwb + 4]  = w1;                                \
        *(uint2*)&plds[wave][qtl][BUF][qrow][dwb + 8]  = w2;                                \
        *(uint2*)&plds[wave][qtl][BUF][qrow][dwb + 12] = w3;                                \
        vf_cur = vf;                                                                        \
    }

#define STEP(IT, SLOT, BUF, PREV)                                                           \
    {                                                                                       \
        short8 pfA = *(short8*)&plds[wave][0][PREV][qrow][quad * 4];                        \
        short8 pfB = *(short8*)&plds[wave][1][PREV][qrow][quad * 4];                        \
        short8 vf_cur;                                                                      \
        QK_PHASE(IT, SLOT, BUF)                                                             \
        accA = __builtin_amdgcn_mfma_f32_16x16x32_bf16(vf_prev, pfA, accA, 0, 0, 0);        \
        accB = __builtin_amdgcn_mfma_f32_16x16x32_bf16(vf_prev, pfB, accB, 0, 0, 0);        \
        vf_prev = vf_cur;                                                                   \
    }

    {
        short8 vf_cur;
        QK_PHASE(0, 0, 0)
        vf_prev = vf_cur;
    }
    for (int p = 0; p < 7; ++p) {
        STEP(2 * p + 1, 1, 1, 0)
        STEP(2 * p + 2, 0, 0, 1)
    }
    STEP(15, 1, 1, 0)
    {
        short8 pfA = *(short8*)&plds[wave][0][1][qrow][quad * 4];
        short8 pfB = *(short8*)&plds[wave][1][1][qrow][quad * 4];
        accA = __builtin_amdgcn_mfma_f32_16x16x32_bf16(vf_prev, pfA, accA, 0, 0, 0);
        accB = __builtin_amdgcn_mfma_f32_16x16x32_bf16(vf_prev, pfB, accB, 0, 0, 0);
    }
#undef STEP
#undef QK_PHASE

    float ltot = l + __shfl_xor(l, 32, 64);

    float* pb0 = partial + (size_t)Tbase * 288;
    *(f32x4*)&pb0[qrow * 16 + quad * 4] = accA;
    float* pb1 = partial + (size_t)(Tbase + T1off) * 288;
    *(f32x4*)&pb1[qrow * 16 + quad * 4] = accB;
    if (lane < 16)       pb0[272 + q5] = ltot;
    else if (lane < 32)  pb1[272 + (q5 - 16)] = ltot;
}

// ------- merge chunk partials + residual + layernorm (uniform m: plain sums) -------
__global__ __launch_bounds__(256) void merge_ln_kernel(
    const float* __restrict__ partial,
    const float* __restrict__ h_m, const float* __restrict__ h_p,
    const float* __restrict__ gm, const float* __restrict__ bm,
    const float* __restrict__ gp, const float* __restrict__ bp_,
    float* __restrict__ out)
{
    int t = threadIdx.x;
    int grow = blockIdx.x * 4 + (t >> 6);
    int c = t & 63;
    const float *pbase, *hbuf, *g, *bb; float* o; int NC, row;
    if (grow < NM) { pbase = partial;               hbuf = h_m; g = gm; bb = bm;  o = out;            NC = 16; row = grow; }
    else           { pbase = partial + 8192 * 288;  hbuf = h_p; g = gp; bb = bp_; o = out + NM * 64;  NC = 4;  row = grow - NM; }
    int hi = c >> 4, d = c & 15;
    int qt = row >> 4, ql = row & 15;
    const float* base = pbase + (size_t)(qt * 4 + hi) * NC * 288;
    float L = 0.0f, A = 0.0f;
    for (int cc = 0; cc < NC; ++cc) {
        L += base[cc * 288 + 272 + ql];
        A += base[cc * 288 + ql * 16 + d];
    }
    float v = hbuf[(size_t)row * 64 + c] + A / L;
    float s = v;
    #pragma unroll
    for (int o2 = 32; o2 >= 1; o2 >>= 1) s += __shfl_xor(s, o2, 64);
    float mu = s * (1.0f / 64.0f);
    float dv = v - mu;
    float sq = dv * dv;
    #pragma unroll
    for (int o2 = 32; o2 >= 1; o2 >>= 1) sq += __shfl_xor(sq, o2, 64);
    float var = sq * (1.0f / 64.0f);
    o[(size_t)row * 64 + c] = dv * rsqrtf(var + 1e-5f) * g[c] + bb[c];
}

extern "C" void kernel_launch(void* const* d_in, const int* in_sizes, int n_in,
                              void* d_out, int out_size, void* d_ws, size_t ws_size,
                              hipStream_t stream)
{
    const float* x_mol   = (const float*)d_in[0];
    const int*   ei_mol  = (const int*)  d_in[1];
    const float* ea_mol  = (const float*)d_in[2];
    const float* x_prot  = (const float*)d_in[3];
    const int*   ei_prot = (const int*)  d_in[4];
    const float* ea_prot = (const float*)d_in[5];
    const float* mol_w1  = (const float*)d_in[6];
    const float* mol_b1  = (const float*)d_in[7];
    const float* mol_w2  = (const float*)d_in[8];
    const float* mol_b2  = (const float*)d_in[9];
    const float* prot_w1 = (const float*)d_in[10];
    const float* prot_b1 = (const float*)d_in[11];
    const float* prot_w2 = (const float*)d_in[12];
    const float* prot_b2 = (const float*)d_in[13];
    const float* mp_wq = (const float*)d_in[14]; const float* mp_bq = (const float*)d_in[15];
    const float* mp_wk = (const float*)d_in[16]; const float* mp_bk = (const float*)d_in[17];
    const float* mp_wv = (const float*)d_in[18]; const float* mp_bv = (const float*)d_in[19];
    const float* pm_wq = (const float*)d_in[20]; const float* pm_bq = (const float*)d_in[21];
    const float* pm_wk = (const float*)d_in[22]; const float* pm_bk = (const float*)d_in[23];
    const float* pm_wv = (const float*)d_in[24]; const float* pm_bv = (const float*)d_in[25];
    const float* ln_mol_g  = (const float*)d_in[26];
    const float* ln_mol_b  = (const float*)d_in[27];
    const float* ln_prot_g = (const float*)d_in[28];
    const float* ln_prot_b = (const float*)d_in[29];

    float* ws = (float*)d_ws;
    // float region
    float* h_mol   = ws;                         // 131072
    float* h_prot  = h_mol + 131072;             // 524288
    float* partial = h_prot + 524288;            // 16384*288 = 4718592 (mol 0..8191, prot 8192..16383)
    // h0 bf16 aliases partial (dead before attn writes partial)
    unsigned short* h0b_mol  = (unsigned short*)partial;      // 131072 shorts
    unsigned short* h0b_prot = h0b_mol + 131072;              // 524288 shorts
    // int region
    int* ip      = (int*)(partial + 4718592);
    int* cnt_m   = ip;                 // 2048
    int* cnt_p   = cnt_m + 2048;       // 8192
    int* norms   = cnt_p + 8192;       // 4  (0=Qm,1=Km,2=Qp,3=Kp; float bits)
    int* start_m = norms + 4;          // 2052 (2049 used)
    int* start_p = start_m + 2052;     // 8196 (8193 used)
    int* cur_m   = start_p + 8196;     // 2048
    int* cur_p   = cur_m + 2048;       // 8192
    int* pidx_m  = cur_p + 8192;       // 32768
    int* pidx_p  = pidx_m + 32768;     // 262144
    // bf16 region
    unsigned short* bf = (unsigned short*)(pidx_p + 262144);
    unsigned short* Qm  = bf;            // 131072
    unsigned short* Km  = Qm + 131072;   // 131072
    unsigned short* Vtm = Km + 131072;   // 131072  [64][NM]
    unsigned short* Qp  = Vtm + 131072;  // 524288
    unsigned short* Kp  = Qp + 524288;   // 524288
    unsigned short* Vtp = Kp + 524288;   // 524288  [64][NP]
    unsigned short* wt  = Vtp + 524288;  // 40960 (10 x 64x64 bf16 transposed weights)

    hipMemsetAsync(cnt_m, 0, (size_t)(2048 + 8192 + 4) * sizeof(int), stream);

    const int EB = (EM + EP) / 256;   // 1152
    // fused: blocks 0..159 = weight prep; 160..160+EB-1 = histogram
    prep_hist_kernel<<<160 + EB, 256, 0, stream>>>(
        mol_w1, mol_w2, mp_wq, pm_wk, pm_wv,
        prot_w1, prot_w2, pm_wq, mp_wk, mp_wv, wt,
        ei_mol, ei_prot, cnt_m, cnt_p);
    scan_kernel<<<2, 256, 0, stream>>>(cnt_m, cnt_p, start_m, start_p, cur_m, cur_p);
    scatter_kernel<<<EB, 256, 0, stream>>>(ei_mol, ei_prot, cur_m, cur_p, pidx_m, pidx_p);
    node_aggr_kernel<<<(NM + NP) / 4, 256, 0, stream>>>(
        x_mol, ea_mol, start_m, pidx_m,
        x_prot, ea_prot, start_p, pidx_p, h0b_mol, h0b_prot);

    mlp_qkv_kernel<<<(NM + NP) / 16, 64, 0, stream>>>(
        h0b_mol, h0b_prot, wt,
        mol_b1, mol_b2, mp_bq, pm_bk, pm_bv,
        prot_b1, prot_b2, pm_bq, mp_bk, mp_bv,
        h_mol, h_prot, Qm, Km, Vtm, Qp, Kp, Vtp, norms);

    // both directions, 512-key chunks: 2048 blocks x 4 waves = 8192 tasks
    attn_kernel<<<2048, 256, 0, stream>>>(Qm, Km, Vtm, Qp, Kp, Vtp, norms, partial);

    float* out = (float*)d_out;
    merge_ln_kernel<<<(NM + NP) / 4, 256, 0, stream>>>(
        partial, h_mol, h_prot, ln_mol_g, ln_mol_b, ln_prot_g, ln_prot_b, out);
}